// Round 1
// baseline (105.872 us; speedup 1.0000x reference)
//
#include <hip/hip_runtime.h>

// SupNet pair-distance head:
//   rp[j][o] = sum_d z[j][d]*W1[o][d] + b1[o]        (o < 256, d < 128)
//   cp[i][o] = sum_d z[i][d]*W1[o][128+d]
//   h[i,j,c]  = relu(rp[j][c] + cp[i][c])
//   h2[i,j,n] = relu(sum_c h*W2[n][c] + b2[n])
//   out[i,j,o]= sum_n h2*Wf[o][n] + bf[o]
//
// Main GEMM: M = 768*768 pair-rows, K=256, N=128, bf16 MFMA 16x16x32.

typedef __attribute__((ext_vector_type(8))) __bf16 bf16x8;
typedef __attribute__((ext_vector_type(4))) float f32x4;

#define NCELL 768
#define DIM   128
#define C1    256
#define C2    128
#define JBLK  128

// ---------------------------------------------------------------- prep: rp/cp
__global__ __launch_bounds__(256) void prep_rc(const float* __restrict__ z,
                                               const float* __restrict__ W1,
                                               const float* __restrict__ b1,
                                               float* __restrict__ rp,
                                               float* __restrict__ cp) {
    const int j = blockIdx.x;     // cell index
    const int o = threadIdx.x;    // output channel 0..255
    __shared__ float zl[DIM];
    if (o < DIM) zl[o] = z[(size_t)j * DIM + o];
    __syncthreads();

    const f32x4* w4 = (const f32x4*)(W1 + (size_t)o * (2 * DIM));
    const f32x4* z4 = (const f32x4*)zl;
    float a1 = 0.f, a2 = 0.f;
#pragma unroll 8
    for (int d4 = 0; d4 < DIM / 4; ++d4) {
        f32x4 zv = z4[d4];
        f32x4 wa = w4[d4];
        f32x4 wb = w4[DIM / 4 + d4];
#pragma unroll
        for (int e = 0; e < 4; ++e) {
            a1 = fmaf(zv[e], wa[e], a1);
            a2 = fmaf(zv[e], wb[e], a2);
        }
    }
    rp[(size_t)j * C1 + o] = a1 + b1[o];   // fold b1 into rp
    cp[(size_t)j * C1 + o] = a2;
}

// ---------------------------------------------------------------- prep: W2 -> bf16
__global__ __launch_bounds__(256) void prep_w2(const float* __restrict__ W2,
                                               __bf16* __restrict__ w2b) {
    const int t = blockIdx.x * 256 + threadIdx.x;  // 0..32767
    w2b[t] = (__bf16)W2[t];
}

// ---------------------------------------------------------------- main kernel
// grid = (6, 768): blockIdx.x = j-block (128 j's), blockIdx.y = i.
// 256 threads = 4 waves; wave w owns rows [w*32, w*32+32), all 128 N-cols.
// LDS: h-tile [128][128] bf16 (swizzled) + W2-tile [128][128] bf16 (swizzled)
//      = 64 KB; K=256 processed in two 128-column halves.
__global__ __launch_bounds__(256) void pair_head(const float* __restrict__ rp,
                                                 const float* __restrict__ cp,
                                                 const __bf16* __restrict__ w2b,
                                                 const float* __restrict__ b2,
                                                 const float* __restrict__ Wf,
                                                 const float* __restrict__ bfv,
                                                 float* __restrict__ out) {
    __shared__ char smem[65536];
    char* hbase = smem;           // 128 rows * 256 B, XOR-swizzled
    char* wbase = smem + 32768;   // 128 rows * 256 B, XOR-swizzled

    const int tid = threadIdx.x;
    const int i   = blockIdx.y;
    const int j0  = blockIdx.x * JBLK;

    const int w  = tid >> 6;   // wave id 0..3
    const int l  = tid & 63;   // lane
    const int lm = l & 15;     // M/N index within fragment
    const int lk = l >> 4;     // k-chunk 0..3

    f32x4 acc[2][8];
#pragma unroll
    for (int mi = 0; mi < 2; ++mi)
#pragma unroll
        for (int ni = 0; ni < 8; ++ni)
            acc[mi][ni] = f32x4{0.f, 0.f, 0.f, 0.f};

    const float* cpi = cp + (size_t)i * C1;

    for (int half = 0; half < 2; ++half) {
        if (half) __syncthreads();
        const int cbase = half * 128;   // column offset into K=256

        // ---- stage h = relu(rp[j]+cp[i]) bf16, swizzled. 128 rows x 16 chunks.
#pragma unroll
        for (int it = 0; it < 8; ++it) {
            int q   = it * 256 + tid;
            int row = q >> 4;          // 0..127  (j - j0)
            int cc  = q & 15;          // 16B chunk within row
            const f32x4* r4 = (const f32x4*)(rp + (size_t)(j0 + row) * C1 + cbase + cc * 8);
            const f32x4* c4 = (const f32x4*)(cpi + cbase + cc * 8);
            f32x4 r0 = r4[0], r1 = r4[1];
            f32x4 c0 = c4[0], c1 = c4[1];
            bf16x8 hv;
#pragma unroll
            for (int e = 0; e < 4; ++e) {
                hv[e]     = (__bf16)fmaxf(r0[e] + c0[e], 0.f);
                hv[e + 4] = (__bf16)fmaxf(r1[e] + c1[e], 0.f);
            }
            int addr = (row << 8) + (cc << 4);
            addr ^= (row & 7) << 4;
            *(bf16x8*)(hbase + addr) = hv;
        }
        // ---- stage W2 half, bf16, swizzled.
#pragma unroll
        for (int it = 0; it < 8; ++it) {
            int q   = it * 256 + tid;
            int row = q >> 4;          // output channel n
            int cc  = q & 15;
            bf16x8 wv = *(const bf16x8*)(w2b + (size_t)row * C1 + cbase + cc * 8);
            int addr = (row << 8) + (cc << 4);
            addr ^= (row & 7) << 4;
            *(bf16x8*)(wbase + addr) = wv;
        }
        __syncthreads();

        // ---- GEMM over this K-half: 4 k-steps of 32
#pragma unroll
        for (int ks = 0; ks < 4; ++ks) {
            bf16x8 a[2], b[8];
#pragma unroll
            for (int mi = 0; mi < 2; ++mi) {
                int row  = w * 32 + mi * 16 + lm;
                int addr = (row << 8) + (ks << 6) + (lk << 4);
                addr ^= (row & 7) << 4;
                a[mi] = *(const bf16x8*)(hbase + addr);
            }
#pragma unroll
            for (int ni = 0; ni < 8; ++ni) {
                int row  = ni * 16 + lm;
                int addr = (row << 8) + (ks << 6) + (lk << 4);
                addr ^= (row & 7) << 4;
                b[ni] = *(const bf16x8*)(wbase + addr);
            }
#pragma unroll
            for (int mi = 0; mi < 2; ++mi)
#pragma unroll
                for (int ni = 0; ni < 8; ++ni)
                    acc[mi][ni] = __builtin_amdgcn_mfma_f32_16x16x32_bf16(
                        a[mi], b[ni], acc[mi][ni], 0, 0, 0);
        }
    }

    // ---- epilogue: h2 = relu(acc + b2); out = Wf . h2 + bf (fp32 in regs)
    float b2v[8], wf0[8], wf1[8];
#pragma unroll
    for (int ni = 0; ni < 8; ++ni) {
        int col = ni * 16 + lm;
        b2v[ni] = b2[col];
        wf0[ni] = Wf[col];
        wf1[ni] = Wf[C2 + col];
    }
    const float bf0 = bfv[0], bf1 = bfv[1];

#pragma unroll
    for (int mi = 0; mi < 2; ++mi) {
#pragma unroll
        for (int r = 0; r < 4; ++r) {
            float p0 = 0.f, p1 = 0.f;
#pragma unroll
            for (int ni = 0; ni < 8; ++ni) {
                float hv = fmaxf(acc[mi][ni][r] + b2v[ni], 0.f);
                p0 = fmaf(wf0[ni], hv, p0);
                p1 = fmaf(wf1[ni], hv, p1);
            }
            // reduce across the 16 lanes holding the 16 N-columns of each frag
            p0 += __shfl_xor(p0, 1);  p1 += __shfl_xor(p1, 1);
            p0 += __shfl_xor(p0, 2);  p1 += __shfl_xor(p1, 2);
            p0 += __shfl_xor(p0, 4);  p1 += __shfl_xor(p1, 4);
            p0 += __shfl_xor(p0, 8);  p1 += __shfl_xor(p1, 8);
            if (lm == 0) {
                int rowg = w * 32 + mi * 16 + lk * 4 + r;   // j - j0
                float* op = out + ((size_t)i * NCELL + (j0 + rowg)) * 2;
                op[0] = p0 + bf0;
                op[1] = p1 + bf1;
            }
        }
    }
}

// ---------------------------------------------------------------- launcher
extern "C" void kernel_launch(void* const* d_in, const int* in_sizes, int n_in,
                              void* d_out, int out_size, void* d_ws, size_t ws_size,
                              hipStream_t stream) {
    const float* z   = (const float*)d_in[0];
    const float* W1  = (const float*)d_in[1];
    const float* b1  = (const float*)d_in[2];
    const float* W2  = (const float*)d_in[3];
    const float* b2  = (const float*)d_in[4];
    const float* Wf  = (const float*)d_in[5];
    const float* bfv = (const float*)d_in[6];
    float* out = (float*)d_out;

    float*  rp  = (float*)d_ws;                    // 768*256 f32
    float*  cp  = rp + NCELL * C1;                 // 768*256 f32
    __bf16* w2b = (__bf16*)(cp + NCELL * C1);      // 128*256 bf16

    prep_rc<<<NCELL, 256, 0, stream>>>(z, W1, b1, rp, cp);
    prep_w2<<<C2 * C1 / 256, 256, 0, stream>>>(W2, w2b);

    dim3 grid(NCELL / JBLK, NCELL, 1);             // (6, 768)
    pair_head<<<grid, 256, 0, stream>>>(rp, cp, w2b, b2, Wf, bfv, out);
}